// Round 2
// baseline (313.862 us; speedup 1.0000x reference)
//
#include <hip/hip_runtime.h>

// Reference: conv3d + bias + GroupNorm output is finite everywhere;
// clip(min(y, 0.25), 0.25, 1.0) == 0.25 for all finite y. The whole op is a
// constant fill of 0.25f over [8, 32, 62, 62, 62] = 61,011,968 fp32 (244 MB).
//
// Pure write-bound kernel:
//  - grid-stride loop, bounded grid (2048 blocks x 256 thr) -> full occupancy,
//    ~29 stores/thread, amortizes block dispatch vs 59,582 one-shot blocks.
//  - nontemporal 16B stores via native ext_vector type (HIP float4 is a class
//    and is rejected by __builtin_nontemporal_store).
//  - tail outside the hot loop (n % 4 == 0 for this shape anyway).

typedef float floatx4 __attribute__((ext_vector_type(4)));

__global__ __launch_bounds__(256) void fill_quarter_kernel(float* __restrict__ out,
                                                           long long n) {
    const long long n4 = n >> 2;                       // float4 count
    const floatx4 v = {0.25f, 0.25f, 0.25f, 0.25f};
    floatx4* __restrict__ out4 = reinterpret_cast<floatx4*>(out);

    const long long stride = (long long)gridDim.x * blockDim.x;
    for (long long i = (long long)blockIdx.x * blockDim.x + threadIdx.x;
         i < n4; i += stride) {
        __builtin_nontemporal_store(v, out4 + i);
    }

    // Scalar tail (n % 4 != 0) — not taken for this shape, kept for safety.
    if (blockIdx.x == 0 && threadIdx.x == 0) {
        for (long long j = n4 << 2; j < n; ++j) out[j] = 0.25f;
    }
}

extern "C" void kernel_launch(void* const* d_in, const int* in_sizes, int n_in,
                              void* d_out, int out_size, void* d_ws, size_t ws_size,
                              hipStream_t stream) {
    (void)d_in; (void)in_sizes; (void)n_in; (void)d_ws; (void)ws_size;
    float* out = (float*)d_out;
    long long n = (long long)out_size;                  // 61,011,968 floats
    long long n4 = (n + 3) >> 2;

    const int block = 256;
    long long grid_needed = (n4 + block - 1) / block;
    // 2048 blocks = 256 CU x 8 blocks/CU -> full occupancy, grid-stride the rest.
    int grid = (int)(grid_needed < 2048 ? grid_needed : 2048);

    fill_quarter_kernel<<<grid, block, 0, stream>>>(out, n);
}